// Round 9
// baseline (20460.158 us; speedup 1.0000x reference)
//
#include <hip/hip_runtime.h>
#include <stdint.h>

#define S_LEN 2048
#define BATCH 32
#define EDIM  512
#define HDIM  512
#define NSLICE 32      // workgroups total; each owns slice sl for BOTH dirs
#define SCOLS  16      // HDIM / NSLICE : h columns owned per WG
#define NG     48      // 3 gates * SCOLS gate-rows per WG = 3 exact MFMA tiles
#define NKH    8       // 8 K-slices of 64 (one per wave)
#define NTHREADS 512   // 8 waves; wave kh owns k in [kh*64, kh*64+64)
#define LPAD   50      // LDS row pitch: stride 200B -> exact 2-way banks (free)

typedef __attribute__((ext_vector_type(8))) short bf16x8;  // 8 bf16 = 4 VGPRs
typedef __attribute__((ext_vector_type(8))) float f32x8;
typedef __attribute__((ext_vector_type(4))) float f32x4;

__device__ __forceinline__ unsigned short f2bf(float f) {
    union { float f; unsigned int i; } v; v.f = f;
    unsigned int u = v.i;
    return (unsigned short)((u + 0x7fffu + ((u >> 16) & 1u)) >> 16);  // RNE
}
__device__ __forceinline__ bf16x8 cvt8(f32x8 v) {
    bf16x8 r;
#pragma unroll
    for (int i = 0; i < 8; ++i) r[i] = (short)f2bf(v[i]);
    return r;
}

// One direction's half-step. v8's proven sc1/flag protocol verbatim; geometry
// K-split-8 (wave kh: k-slice 64, both m-tiles). accx parks to LDS BEFORE the
// poll (caps register peak ~190 < 256). Poll fan-in = 4 slices (only the
// producers of this wave's k-slice). All state passed by reference with
// static indices -> stays in registers after inlining (rule #20 safe).
template<int DIR>
__device__ __forceinline__ void half_step(
    const int t, const int sl, const int tid,
    const bf16x8 (&wf)[3][2], const bf16x8 (&hf)[3][2],
    bf16x8 (&xa)[2][2],
    float (*gxl)[BATCH][LPAD], float (*ghl)[BATCH][LPAD],
    float (*hloc)[SCOLS],
    const float* bih_s, const float* bhh_s,
    const float* __restrict__ xseq,
    unsigned short* __restrict__ h_buf,
    int* __restrict__ flags,
    float* __restrict__ out)
{
    const int lane = tid & 63;
    const int kh   = tid >> 6;          // 0..7
    const int l15  = lane & 15;
    const int q8   = (lane >> 4) * 8;   // frag k-offset within 32-wide window
    const int rj   = (lane >> 4) * 4;   // C-frag row base

    // ---- gx partials = x(t) @ Wih^T : registers only, park to LDS early ----
#pragma unroll
    for (int ti = 0; ti < 3; ++ti)
#pragma unroll
        for (int mt = 0; mt < 2; ++mt) {
            f32x4 a = {0.f, 0.f, 0.f, 0.f};
#pragma unroll
            for (int kt = 0; kt < 2; ++kt)
                a = __builtin_amdgcn_mfma_f32_16x16x32_bf16(
                        xa[mt][kt], wf[ti][kt], a, 0, 0, 0);
#pragma unroll
            for (int j = 0; j < 4; ++j)
                gxl[kh][mt * 16 + rj + j][ti * 16 + l15] = a[j];
        }

    // ---- poll only our 4 producer slices, then load our 4KB of h(t-1) ----
    bf16x8 ha[2][2] = {};
    if (t > 0) {
        int* fp = flags + DIR * NSLICE + kh * 4 + (lane & 3);
        for (;;) {
            int f = __hip_atomic_load(fp, __ATOMIC_RELAXED,
                                      __HIP_MEMORY_SCOPE_AGENT);
            if (__all(f >= t)) break;
        }
        const unsigned short* hp0 = h_buf
            + ((size_t)((t & 1) * 2 + DIR)) * (BATCH * HDIM)
            + (size_t)l15 * HDIM + kh * 64 + q8;
        const unsigned short* hp1 = hp0 + 16 * HDIM;
        asm volatile(
            "global_load_dwordx4 %0, %4, off sc1\n\t"
            "global_load_dwordx4 %1, %4, off offset:64 sc1\n\t"
            "global_load_dwordx4 %2, %5, off sc1\n\t"
            "global_load_dwordx4 %3, %5, off offset:64 sc1\n\t"
            "s_waitcnt vmcnt(0)"
            : "=v"(ha[0][0]), "=v"(ha[0][1]), "=v"(ha[1][0]), "=v"(ha[1][1])
            : "v"(hp0), "v"(hp1)
            : "memory");
    }

    // ---- gh partials = h(t-1) @ Whh^T -> LDS ----
#pragma unroll
    for (int ti = 0; ti < 3; ++ti)
#pragma unroll
        for (int mt = 0; mt < 2; ++mt) {
            f32x4 a = {0.f, 0.f, 0.f, 0.f};
#pragma unroll
            for (int kt = 0; kt < 2; ++kt)
                a = __builtin_amdgcn_mfma_f32_16x16x32_bf16(
                        ha[mt][kt], hf[ti][kt], a, 0, 0, 0);
#pragma unroll
            for (int j = 0; j < 4; ++j)
                ghl[kh][mt * 16 + rj + j][ti * 16 + l15] = a[j];
        }

    __syncthreads();

    // ---- pointwise GRU cell: sum 8 partials, proven formulas ----
    {
        const int b = tid >> 4, c = tid & 15;
        float sxr = 0.f, shr = 0.f, sxz = 0.f, shz = 0.f, sxn = 0.f, shn = 0.f;
#pragma unroll
        for (int k8 = 0; k8 < NKH; ++k8) {
            sxr += gxl[k8][b][c];        shr += ghl[k8][b][c];
            sxz += gxl[k8][b][16 + c];   shz += ghl[k8][b][16 + c];
            sxn += gxl[k8][b][32 + c];   shn += ghl[k8][b][32 + c];
        }
        const float xr = sxr + bih_s[c],      hr = shr + bhh_s[c];
        const float xz = sxz + bih_s[16 + c], hz = shz + bhh_s[16 + c];
        const float xn = sxn + bih_s[32 + c], hn = shn + bhh_s[32 + c];
        const float r  = 1.f / (1.f + __expf(-(xr + hr)));
        const float z  = 1.f / (1.f + __expf(-(xz + hz)));
        const float pre = xn + r * hn;
        const float n_  = 2.f / (1.f + __expf(-2.f * pre)) - 1.f;  // tanh
        const float hnew = (1.f - z) * n_ + z * hloc[b][c];
        hloc[b][c] = hnew;
        if (t < S_LEN - 1) {
            // pair adjacent cols -> one dword sc1 (write-through to LLC)
            const float ho = __shfl_xor(hnew, 1);
            if ((c & 1) == 0) {
                unsigned int pack = (unsigned int)f2bf(hnew)
                                  | ((unsigned int)f2bf(ho) << 16);
                unsigned int* dst = (unsigned int*)(h_buf
                    + ((size_t)(((t + 1) & 1) * 2 + DIR)) * (BATCH * HDIM)
                    + (size_t)b * HDIM + sl * SCOLS + c);
                asm volatile("global_store_dword %0, %1, off sc1"
                             :: "v"(dst), "v"(pack) : "memory");
            }
        } else {
            out[(size_t)b * (2 * HDIM) + DIR * HDIM + sl * SCOLS + c] = hnew;
        }
    }
    // drain sc1 stores to the LLC before the barrier, then publish
    asm volatile("s_waitcnt vmcnt(0)" ::: "memory");
    __syncthreads();

    if (t < S_LEN - 1) {
        if (tid == 0) {
            __hip_atomic_store(&flags[DIR * NSLICE + sl], t + 1,
                               __ATOMIC_RELAXED, __HIP_MEMORY_SCOPE_AGENT);
        }
        // ---- tail: load + cvt x(t+1); hidden under the OTHER dir's half ----
        const int txn = DIR ? (S_LEN - 2 - t) : (t + 1);
        const float* xq = xseq + (size_t)txn * (BATCH * EDIM);
#pragma unroll
        for (int mt = 0; mt < 2; ++mt)
#pragma unroll
            for (int kt = 0; kt < 2; ++kt)
                xa[mt][kt] = cvt8(*(const f32x8*)(xq
                    + (size_t)(mt * 16 + l15) * EDIM + kh * 64 + kt * 32 + q8));
    }
}

// 32 WGs x 512 threads, 1 WG/CU. WG sl owns h-cols [sl*16, sl*16+16) for BOTH
// directions, executed as interleaved halves F,B per timestep. Each chain's
// flag-visibility window is covered by the other chain's half -> discovery
// stall ~0. Same fence-free sc1 protocol as v0/v4/v8.
__global__ void
__attribute__((amdgpu_flat_work_group_size(NTHREADS, NTHREADS)))
__attribute__((amdgpu_waves_per_eu(2, 2)))
gru_persistent(const float* __restrict__ xseq,   // [S][B][E] fp32
               const float* __restrict__ Wih_f,
               const float* __restrict__ Whh_f,
               const float* __restrict__ bih_f,
               const float* __restrict__ bhh_f,
               const float* __restrict__ Wih_b,
               const float* __restrict__ Whh_b,
               const float* __restrict__ bih_b,
               const float* __restrict__ bhh_b,
               float* __restrict__ out,            // [B][2H] fp32
               int* __restrict__ flags,            // [2][32]
               unsigned short* __restrict__ h_buf) // [2 buf][2 dir][B][H] bf16
{
    const int sl   = blockIdx.x;      // 0..31
    const int tid  = threadIdx.x;
    const int lane = tid & 63;
    const int kh   = tid >> 6;
    const int l15  = lane & 15;
    const int q8   = (lane >> 4) * 8;

    __shared__ float gxl[NKH][BATCH][LPAD];
    __shared__ float ghl[NKH][BATCH][LPAD];
    __shared__ float hloc2[2][BATCH][SCOLS];
    __shared__ float bihS[2][NG], bhhS[2][NG];

    // ---- persistent weight B-fragments, both dirs (fp32 -> bf16 once) ----
    // wave kh: 3 gate tiles x 2 kt (k = kh*64 + kt*32 + q8 + j), n = l15
    bf16x8 wfF[3][2], hfF[3][2], wfB[3][2], hfB[3][2];
#pragma unroll
    for (int ti = 0; ti < 3; ++ti) {
        const int row = ti * HDIM + sl * SCOLS + l15;
#pragma unroll
        for (int kt = 0; kt < 2; ++kt) {
            const int k = kh * 64 + kt * 32 + q8;
            wfF[ti][kt] = cvt8(*(const f32x8*)(Wih_f + (size_t)row * EDIM + k));
            hfF[ti][kt] = cvt8(*(const f32x8*)(Whh_f + (size_t)row * HDIM + k));
            wfB[ti][kt] = cvt8(*(const f32x8*)(Wih_b + (size_t)row * EDIM + k));
            hfB[ti][kt] = cvt8(*(const f32x8*)(Whh_b + (size_t)row * HDIM + k));
        }
    }
    if (tid < NG) {
        const int row = (tid >> 4) * HDIM + sl * SCOLS + (tid & 15);
        bihS[0][tid] = bih_f[row];  bhhS[0][tid] = bhh_f[row];
        bihS[1][tid] = bih_b[row];  bhhS[1][tid] = bhh_b[row];
    }
    ((float*)hloc2)[tid] = 0.f;               // h0 = 0 (both dirs, 1024 items)
    ((float*)hloc2)[tid + NTHREADS] = 0.f;
    __syncthreads();

    // ---- prologue: xa frags for t=0 of each dir; ha handled inside (t=0) ----
    bf16x8 xaF[2][2], xaB[2][2];
#pragma unroll
    for (int mt = 0; mt < 2; ++mt)
#pragma unroll
        for (int kt = 0; kt < 2; ++kt) {
            const size_t off = (size_t)(mt * 16 + l15) * EDIM + kh * 64 + kt * 32 + q8;
            xaF[mt][kt] = cvt8(*(const f32x8*)(xseq + off));
            xaB[mt][kt] = cvt8(*(const f32x8*)(xseq
                              + (size_t)(S_LEN - 1) * (BATCH * EDIM) + off));
        }

    for (int t = 0; t < S_LEN; ++t) {
        half_step<0>(t, sl, tid, wfF, hfF, xaF, gxl, ghl, hloc2[0],
                     bihS[0], bhhS[0], xseq, h_buf, flags, out);
        half_step<1>(t, sl, tid, wfB, hfB, xaB, gxl, ghl, hloc2[1],
                     bihS[1], bhhS[1], xseq, h_buf, flags, out);
    }
}

extern "C" void kernel_launch(void* const* d_in, const int* in_sizes, int n_in,
                              void* d_out, int out_size, void* d_ws, size_t ws_size,
                              hipStream_t stream) {
    // setup_inputs order: seq_length, embedding_seq, Wih_f, Whh_f, bih_f, bhh_f,
    //                     Wih_b, Whh_b, bih_b, bhh_b   (float32 tensors)
    const float* xseq  = (const float*)d_in[1];
    const float* Wih_f = (const float*)d_in[2];
    const float* Whh_f = (const float*)d_in[3];
    const float* bih_f = (const float*)d_in[4];
    const float* bhh_f = (const float*)d_in[5];
    const float* Wih_b = (const float*)d_in[6];
    const float* Whh_b = (const float*)d_in[7];
    const float* bih_b = (const float*)d_in[8];
    const float* bhh_b = (const float*)d_in[9];

    // ws layout: [0,256) flags int[2][32]; [512, 512+256K) h double buffers
    // (h_buf needs no zeroing: t=0 uses in-register zero ha, never reads it)
    int* flags = (int*)d_ws;
    unsigned short* h_buf = (unsigned short*)((char*)d_ws + 512);
    hipMemsetAsync(d_ws, 0, 512, stream);   // zero flags (graph-safe)

    hipLaunchKernelGGL(gru_persistent, dim3(NSLICE), dim3(NTHREADS), 0, stream,
                       xseq, Wih_f, Whh_f, bih_f, bhh_f,
                       Wih_b, Whh_b, bih_b, bhh_b,
                       (float*)d_out, flags, h_buf);
}